// Round 3
// baseline (199.945 us; speedup 1.0000x reference)
//
#include <hip/hip_runtime.h>
#include <hip/hip_bf16.h>

// Problem: B=32, N=128, T=96, H=64, TF=24.  ALL inputs/outputs are FLOAT32
// (reference setup_inputs uses jnp.float32 everywhere) — prior rounds read
// them as bf16, which decodes fp32 mantissa halves as random-exponent bf16
// (~1/256 are NaN encodings) => guaranteed NaN. Cast per the contract.
//
// A_norm = ones(N,N)/N  =>  every GCN layer outputs the node-MEAN (node-
// uniform); all downstream ops preserve node-uniformity. The model collapses
// to per-batch H-vectors: node dim appears only in the initial mean over
// nodes and the final broadcast.
//
// Single fused kernel, one block per batch, 256 threads (4 waves), all
// intermediates in LDS/registers, zero global workspace.

#define BN 32
#define NN 128
#define TT 96
#define HH 64
#define TFC 24

__device__ __forceinline__ float fast_tanh(float x) {
    x = fminf(fmaxf(x, -15.f), 15.f);
    float e = __expf(2.f * x);
    return (e - 1.f) / (e + 1.f);
}
__device__ __forceinline__ float fast_sigmoid(float x) {
    return 1.f / (1.f + __expf(-x));
}
__device__ __forceinline__ float wave_sum(float v) {
#pragma unroll
    for (int off = 32; off > 0; off >>= 1) v += __shfl_xor(v, off, 64);
    return v;
}
__device__ __forceinline__ float wave_max(float v) {
#pragma unroll
    for (int off = 32; off > 0; off >>= 1) v = fmaxf(v, __shfl_xor(v, off, 64));
    return v;
}

__global__ __launch_bounds__(256, 1) void fused_kernel(
    const float* __restrict__ x,    const float* __restrict__ Ws1,
    const float* __restrict__ bs1,  const float* __restrict__ Ws2,
    const float* __restrict__ bs2,  const float* __restrict__ Wa1,
    const float* __restrict__ ba1,  const float* __restrict__ Wa2,
    const float* __restrict__ Wih,  const float* __restrict__ bih,
    const float* __restrict__ bhh,  const float* __restrict__ Wo1,
    const float* __restrict__ bo1p, const float* __restrict__ Wo2,
    const float* __restrict__ bo2p, const float* __restrict__ Wout,
    const float* __restrict__ boutp, float* __restrict__ out)
{
    const int tid  = threadIdx.x;
    const int lane = tid & 63;
    const int w    = tid >> 6;
    const int b    = blockIdx.x;

    __shared__ __align__(16) float xbar[TT];
    __shared__ __align__(16) float h2s[TT][HH];      // 24.5 KB
    __shared__ __align__(16) float atts[TT];
    __shared__ __align__(16) float sA[4][HH];        // per-wave scratch
    __shared__ __align__(16) float sB[4][HH];
    __shared__ __align__(16) float slw[4][TT];
    __shared__ __align__(16) float slp[4][TFC];

    const float4* sAv = (const float4*)&sA[w][0];
    const float4* sBv = (const float4*)&sB[w][0];

    // ---- phase 0: xbar[t] = mean_n x[b,n,t] ----
    if (tid < TT) {
        const float* xb = x + (size_t)b * NN * TT + tid;
        float s = 0.f;
#pragma unroll 8
        for (int n = 0; n < NN; ++n) s += xb[n * TT];
        xbar[tid] = s * (1.f / 128.f);
    }

    // per-lane weight preloads for phase 1 (independent of x)
    const float ws1l = Ws1[lane];
    const float bs1l = bs1[lane];
    const float bs2l = bs2[lane];
    const float ba1l = ba1[lane];
    const float wa2l = Wa2[lane];
    float ws2c[HH], wa1c[HH];
#pragma unroll
    for (int h = 0; h < HH; ++h) {
        ws2c[h] = Ws2[h * HH + lane];
        wa1c[h] = Wa1[h * HH + lane];
    }
    __syncthreads();

    // ---- phase 1: spatial GCN + attention logits, 24 t's per wave ----
    for (int i = 0; i < TT / 4; ++i) {
        const int t = w * (TT / 4) + i;
        const float s = xbar[t];
        // h1[h] = relu(s*Ws1[h]+bs1[h]); lane = h; wave-private sA slice
        sA[w][lane] = fmaxf(s * ws1l + bs1l, 0.f);
        __syncthreads();   // uniform across all 256 threads
        float a0 = 0.f, a1 = 0.f, a2 = 0.f, a3 = 0.f;
#pragma unroll
        for (int h4 = 0; h4 < HH / 4; ++h4) {
            float4 v = sAv[h4];
            a0 += v.x * ws2c[4 * h4 + 0];
            a1 += v.y * ws2c[4 * h4 + 1];
            a2 += v.z * ws2c[4 * h4 + 2];
            a3 += v.w * ws2c[4 * h4 + 3];
        }
        const float h2v = fmaxf(((a0 + a1) + (a2 + a3)) + bs2l, 0.f);
        h2s[t][lane] = h2v;
        sB[w][lane] = h2v;
        __syncthreads();
        a0 = a1 = a2 = a3 = 0.f;
#pragma unroll
        for (int h4 = 0; h4 < HH / 4; ++h4) {
            float4 v = sBv[h4];
            a0 += v.x * wa1c[4 * h4 + 0];
            a1 += v.y * wa1c[4 * h4 + 1];
            a2 += v.z * wa1c[4 * h4 + 2];
            a3 += v.w * wa1c[4 * h4 + 3];
        }
        const float g = fast_tanh(((a0 + a1) + (a2 + a3)) + ba1l);
        const float att = wave_sum(g * wa2l);   // ba2 dropped: softmax shift-inv
        if (lane == 0) atts[t] = att;
    }
    __syncthreads();

    // ---- phase 2: softmax over t + nf + GRU (redundant per wave) ----
    {
        const float a0s = atts[lane];
        const float a1s = (lane < TT - 64) ? atts[64 + lane] : -1e30f;
        const float m = wave_max(fmaxf(a0s, a1s));
        const float e0 = __expf(a0s - m);
        const float e1 = (lane < TT - 64) ? __expf(a1s - m) : 0.f;
        const float inv = 1.f / wave_sum(e0 + e1);
        slw[w][lane] = e0 * inv;
        if (lane < TT - 64) slw[w][64 + lane] = e1 * inv;
    }
    __syncthreads();

    float nf = 0.f;
#pragma unroll 8
    for (int t = 0; t < TT; ++t) nf += slw[w][t] * h2s[t][lane];
    sA[w][lane] = nf;
    __syncthreads();

    // one-step GRU, h0=0: W_hh matmul vanishes, b_hh biases remain
    float gr = bih[lane];
    float gz = bih[64 + lane];
    float gn = bih[128 + lane];
#pragma unroll 8
    for (int h = 0; h < HH; ++h) {
        const float v = sA[w][h];
        gr += v * Wih[lane * HH + h];
        gz += v * Wih[(64 + lane) * HH + h];
        gn += v * Wih[(128 + lane) * HH + h];
    }
    const float r = fast_sigmoid(gr + bhh[lane]);
    const float z = fast_sigmoid(gz + bhh[64 + lane]);
    const float n = fast_tanh(gn + r * bhh[128 + lane]);
    float y = (1.f - z) * n;
    __syncthreads();

    // ---- phase 3: ODE weight columns into registers, 23 RK4 steps ----
    float w1c[HH], w2c[HH];
#pragma unroll
    for (int h = 0; h < HH; ++h) {
        w1c[h] = Wo1[h * HH + lane];
        w2c[h] = Wo2[h * HH + lane];
    }
    const float bo1 = bo1p[lane];
    const float bo2 = bo2p[lane];
    const float wo  = Wout[lane];
    const float bo  = boutp[0];

    // f(u) = tanh( tanh(u@W1+b1) @ W2 + b2 ); uniform control flow across waves
    auto f_eval = [&](float u) -> float {
        sA[w][lane] = u;
        __syncthreads();
        float a0 = 0.f, a1 = 0.f, a2 = 0.f, a3 = 0.f;
#pragma unroll
        for (int h4 = 0; h4 < HH / 4; ++h4) {
            float4 v = sAv[h4];
            a0 += v.x * w1c[4 * h4 + 0];
            a1 += v.y * w1c[4 * h4 + 1];
            a2 += v.z * w1c[4 * h4 + 2];
            a3 += v.w * w1c[4 * h4 + 3];
        }
        const float vv = fast_tanh(((a0 + a1) + (a2 + a3)) + bo1);
        sB[w][lane] = vv;
        __syncthreads();
        a0 = a1 = a2 = a3 = 0.f;
#pragma unroll
        for (int h4 = 0; h4 < HH / 4; ++h4) {
            float4 v = sBv[h4];
            a0 += v.x * w2c[4 * h4 + 0];
            a1 += v.y * w2c[4 * h4 + 1];
            a2 += v.z * w2c[4 * h4 + 2];
            a3 += v.w * w2c[4 * h4 + 3];
        }
        return fast_tanh(((a0 + a1) + (a2 + a3)) + bo2);
    };

    {
        const float p = wave_sum(y * wo) + bo;
        if (lane == 0) slp[w][0] = p;
    }

    const float dt = (float)(24.0 / 23.0);
    const float third = 1.f / 3.f;

    for (int st = 0; st < TFC - 1; ++st) {
        const float k1 = f_eval(y);
        const float k2 = f_eval(y + dt * k1 * third);
        const float k3 = f_eval(y + dt * (k2 - k1 * third));
        const float k4 = f_eval(y + dt * (k1 - k2 + k3));
        y = y + dt * (k1 + 3.f * (k2 + k3) + k4) * 0.125f;
        const float p = wave_sum(y * wo) + bo;
        if (lane == 0) slp[w][st + 1] = p;
    }
    __syncthreads();

    // ---- broadcast across nodes: out[b, n, tf] = p[tf] ----
    float* ob = out + (size_t)b * NN * TFC;
#pragma unroll
    for (int i = 0; i < (NN * TFC) / 256; ++i) {
        const int idx = i * 256 + tid;
        const int tf = idx % TFC;
        ob[idx] = slp[w][tf];  // own wave's copy (all copies identical)
    }
}

extern "C" void kernel_launch(void* const* d_in, const int* in_sizes, int n_in,
                              void* d_out, int out_size, void* d_ws, size_t ws_size,
                              hipStream_t stream) {
    (void)in_sizes; (void)n_in; (void)d_ws; (void)ws_size; (void)out_size;
    const float* x    = (const float*)d_in[0];
    const float* Ws1  = (const float*)d_in[1];
    const float* bs1  = (const float*)d_in[2];
    const float* Ws2  = (const float*)d_in[3];
    const float* bs2  = (const float*)d_in[4];
    const float* Wa1  = (const float*)d_in[5];
    const float* ba1  = (const float*)d_in[6];
    const float* Wa2  = (const float*)d_in[7];
    // d_in[8]  = ba2  : unused (softmax shift-invariant)
    const float* Wih  = (const float*)d_in[9];
    // d_in[10] = W_hh : unused (h0 = 0)
    const float* bih  = (const float*)d_in[11];
    const float* bhh  = (const float*)d_in[12];
    const float* Wo1  = (const float*)d_in[13];
    const float* bo1  = (const float*)d_in[14];
    const float* Wo2  = (const float*)d_in[15];
    const float* bo2  = (const float*)d_in[16];
    const float* Wout = (const float*)d_in[17];
    const float* bout = (const float*)d_in[18];

    fused_kernel<<<dim3(BN), dim3(256), 0, stream>>>(
        x, Ws1, bs1, Ws2, bs2, Wa1, ba1, Wa2,
        Wih, bih, bhh, Wo1, bo1, Wo2, bo2, Wout, bout,
        (float*)d_out);
}

// Round 4
// 169.394 us; speedup vs baseline: 1.1804x; 1.1804x over previous
//
#include <hip/hip_runtime.h>

// Problem: B=32, N=128, T=96, H=64, TF=24. All I/O float32.
// A_norm = ones(N,N)/N => every GCN output is the node-mean (node-uniform);
// the model collapses to per-batch H-vectors. Node dim appears only in the
// initial mean over nodes and the final broadcast.
//
// R3 profile: VALUBusy 3.8%, VGPR=112 => compiler demoted the 256-float
// weight "register arrays" to per-iteration reloads; plus 232 full-block
// barriers. This version: readlane-based broadcasts (no LDS, no barriers in
// the sequential phases), wave-0-only ODE, disjoint weight liveness.

#define BN 32
#define NN 128
#define TT 96
#define HH 64
#define TFC 24

__device__ __forceinline__ float rdl(float v, int l) {
    return __int_as_float(__builtin_amdgcn_readlane(__float_as_int(v), l));
}
__device__ __forceinline__ float fast_tanh(float x) {
    x = fminf(fmaxf(x, -15.f), 15.f);
    float e = __expf(2.f * x);
    return (e - 1.f) / (e + 1.f);
}
__device__ __forceinline__ float fast_sigmoid(float x) {
    return 1.f / (1.f + __expf(-x));
}
__device__ __forceinline__ float wave_sum(float v) {
#pragma unroll
    for (int off = 32; off > 0; off >>= 1) v += __shfl_xor(v, off, 64);
    return v;
}
__device__ __forceinline__ float wave_max(float v) {
#pragma unroll
    for (int off = 32; off > 0; off >>= 1) v = fmaxf(v, __shfl_xor(v, off, 64));
    return v;
}

__global__ __launch_bounds__(256, 1) void fused_kernel(
    const float* __restrict__ x,    const float* __restrict__ Ws1,
    const float* __restrict__ bs1,  const float* __restrict__ Ws2,
    const float* __restrict__ bs2,  const float* __restrict__ Wa1,
    const float* __restrict__ ba1,  const float* __restrict__ Wa2,
    const float* __restrict__ Wih,  const float* __restrict__ bih,
    const float* __restrict__ bhh,  const float* __restrict__ Wo1,
    const float* __restrict__ bo1p, const float* __restrict__ Wo2,
    const float* __restrict__ bo2p, const float* __restrict__ Wout,
    const float* __restrict__ boutp, float* __restrict__ out)
{
    const int tid  = threadIdx.x;
    const int lane = tid & 63;
    const int w    = tid >> 6;
    const int b    = blockIdx.x;

    __shared__ float xbar[TT];
    __shared__ float h2s[TT][HH];
    __shared__ float atts[TT];

    // ---- phase 0: xbar[t] = mean_n x[b,n,t] (t contiguous => coalesced) ----
    if (tid < TT) {
        const float* xb = x + (size_t)b * NN * TT + tid;
        float s = 0.f;
#pragma unroll
        for (int n = 0; n < NN; ++n) s += xb[n * TT];
        xbar[tid] = s * (1.f / 128.f);
    }

    // phase-1 per-lane weights (live only through phase 1)
    const float ws1l = Ws1[lane];
    const float bs1l = bs1[lane];
    const float bs2l = bs2[lane];
    const float ba1l = ba1[lane];
    const float wa2l = Wa2[lane];
    float ws2c[HH], wa1c[HH];
#pragma unroll
    for (int h = 0; h < HH; ++h) {
        ws2c[h] = Ws2[h * HH + lane];
        wa1c[h] = Wa1[h * HH + lane];
    }
    __syncthreads();   // barrier 1: xbar ready

    // ---- phase 1: spatial GCN + attention logits, 24 t per wave,
    //      readlane broadcasts, NO barriers, NO LDS round-trips ----
#pragma unroll 1
    for (int i = 0; i < TT / 4; ++i) {
        const int t = w * (TT / 4) + i;
        const float s = xbar[t];                       // uniform LDS read
        const float h1 = fmaxf(fmaf(s, ws1l, bs1l), 0.f);  // lane = h
        float a0 = bs2l, a1 = 0.f, a2 = 0.f, a3 = 0.f;
#pragma unroll
        for (int h = 0; h < HH; h += 4) {
            a0 = fmaf(rdl(h1, h),     ws2c[h],     a0);
            a1 = fmaf(rdl(h1, h + 1), ws2c[h + 1], a1);
            a2 = fmaf(rdl(h1, h + 2), ws2c[h + 2], a2);
            a3 = fmaf(rdl(h1, h + 3), ws2c[h + 3], a3);
        }
        const float h2v = fmaxf((a0 + a1) + (a2 + a3), 0.f);
        h2s[t][lane] = h2v;

        a0 = ba1l; a1 = 0.f; a2 = 0.f; a3 = 0.f;
#pragma unroll
        for (int h = 0; h < HH; h += 4) {
            a0 = fmaf(rdl(h2v, h),     wa1c[h],     a0);
            a1 = fmaf(rdl(h2v, h + 1), wa1c[h + 1], a1);
            a2 = fmaf(rdl(h2v, h + 2), wa1c[h + 2], a2);
            a3 = fmaf(rdl(h2v, h + 3), wa1c[h + 3], a3);
        }
        const float g = fast_tanh((a0 + a1) + (a2 + a3));
        const float att = wave_sum(g * wa2l);          // ba2: shift-invariant
        if (lane == 0) atts[t] = att;
    }
    __syncthreads();   // barrier 2: h2s, atts ready

    if (w != 0) return;   // waves 1-3 done; no barriers remain below

    // ================= wave 0 only: softmax + nf + GRU + ODE =================
    const float a0s = atts[lane];
    const float a1s = (lane < TT - 64) ? atts[64 + lane] : -1e30f;
    const float m = wave_max(fmaxf(a0s, a1s));
    const float e0 = __expf(a0s - m);
    const float e1 = (lane < TT - 64) ? __expf(a1s - m) : 0.f;
    const float inv = 1.f / wave_sum(e0 + e1);
    const float q0 = e0 * inv;
    const float q1 = e1 * inv;

    // nf[lane] = sum_t w[t] * h2[t][lane]; w[t] uniform via readlane
    float nf = 0.f;
#pragma unroll
    for (int t = 0; t < 64; ++t) nf = fmaf(rdl(q0, t), h2s[t][lane], nf);
#pragma unroll
    for (int t = 0; t < 32; ++t) nf = fmaf(rdl(q1, t), h2s[64 + t][lane], nf);

    // one-step GRU, h0=0 (W_hh matmul vanishes; b_hh biases remain)
    float gr = bih[lane];
    float gz = bih[64 + lane];
    float gn = bih[128 + lane];
#pragma unroll
    for (int j = 0; j < HH; j += 4) {
        const float4 wr = *(const float4*)&Wih[(size_t)lane * HH + j];
        const float4 wz = *(const float4*)&Wih[(size_t)(64 + lane) * HH + j];
        const float4 wn = *(const float4*)&Wih[(size_t)(128 + lane) * HH + j];
        const float n0 = rdl(nf, j), n1 = rdl(nf, j + 1);
        const float n2 = rdl(nf, j + 2), n3 = rdl(nf, j + 3);
        gr += n0 * wr.x + n1 * wr.y + n2 * wr.z + n3 * wr.w;
        gz += n0 * wz.x + n1 * wz.y + n2 * wz.z + n3 * wz.w;
        gn += n0 * wn.x + n1 * wn.y + n2 * wn.z + n3 * wn.w;
    }
    const float r = fast_sigmoid(gr + bhh[lane]);
    const float z = fast_sigmoid(gz + bhh[64 + lane]);
    const float n = fast_tanh(gn + r * bhh[128 + lane]);
    float y = (1.f - z) * n;

    // ODE weights: loaded AFTER phase-1 arrays die (disjoint liveness)
    float w1c[HH], w2c[HH];
#pragma unroll
    for (int h = 0; h < HH; ++h) {
        w1c[h] = Wo1[h * HH + lane];
        w2c[h] = Wo2[h * HH + lane];
    }
    const float bo1 = bo1p[lane];
    const float bo2 = bo2p[lane];
    const float wo  = Wout[lane];
    const float bo  = boutp[0];

    // f(u) = tanh( tanh(u@W1+b1) @ W2 + b2 ) — pure registers + readlane
    auto f_eval = [&](float u) -> float {
        float c0 = bo1, c1 = 0.f, c2 = 0.f, c3 = 0.f;
#pragma unroll
        for (int h = 0; h < HH; h += 4) {
            c0 = fmaf(rdl(u, h),     w1c[h],     c0);
            c1 = fmaf(rdl(u, h + 1), w1c[h + 1], c1);
            c2 = fmaf(rdl(u, h + 2), w1c[h + 2], c2);
            c3 = fmaf(rdl(u, h + 3), w1c[h + 3], c3);
        }
        const float v = fast_tanh((c0 + c1) + (c2 + c3));
        c0 = bo2; c1 = 0.f; c2 = 0.f; c3 = 0.f;
#pragma unroll
        for (int h = 0; h < HH; h += 4) {
            c0 = fmaf(rdl(v, h),     w2c[h],     c0);
            c1 = fmaf(rdl(v, h + 1), w2c[h + 1], c1);
            c2 = fmaf(rdl(v, h + 2), w2c[h + 2], c2);
            c3 = fmaf(rdl(v, h + 3), w2c[h + 3], c3);
        }
        return fast_tanh((c0 + c1) + (c2 + c3));
    };

    // output head: p is uniform across lanes after wave_sum; store directly.
    float* ob = out + (size_t)b * NN * TFC;
    {
        const float p = wave_sum(y * wo) + bo;         // traj[0] = hidden
        ob[lane * TFC]        = p;                     // n = lane
        ob[(64 + lane) * TFC] = p;                     // n = lane+64
    }

    const float dt = (float)(24.0 / 23.0);
    const float third = 1.f / 3.f;

#pragma unroll 1
    for (int st = 0; st < TFC - 1; ++st) {
        const float k1 = f_eval(y);
        const float k2 = f_eval(y + dt * k1 * third);
        const float k3 = f_eval(y + dt * (k2 - k1 * third));
        const float k4 = f_eval(y + dt * (k1 - k2 + k3));
        y = y + dt * (k1 + 3.f * (k2 + k3) + k4) * 0.125f;
        const float p = wave_sum(y * wo) + bo;
        ob[lane * TFC + st + 1]        = p;
        ob[(64 + lane) * TFC + st + 1] = p;
    }
}

extern "C" void kernel_launch(void* const* d_in, const int* in_sizes, int n_in,
                              void* d_out, int out_size, void* d_ws, size_t ws_size,
                              hipStream_t stream) {
    (void)in_sizes; (void)n_in; (void)d_ws; (void)ws_size; (void)out_size;
    const float* x    = (const float*)d_in[0];
    const float* Ws1  = (const float*)d_in[1];
    const float* bs1  = (const float*)d_in[2];
    const float* Ws2  = (const float*)d_in[3];
    const float* bs2  = (const float*)d_in[4];
    const float* Wa1  = (const float*)d_in[5];
    const float* ba1  = (const float*)d_in[6];
    const float* Wa2  = (const float*)d_in[7];
    // d_in[8]  = ba2  : unused (softmax shift-invariant)
    const float* Wih  = (const float*)d_in[9];
    // d_in[10] = W_hh : unused (h0 = 0)
    const float* bih  = (const float*)d_in[11];
    const float* bhh  = (const float*)d_in[12];
    const float* Wo1  = (const float*)d_in[13];
    const float* bo1  = (const float*)d_in[14];
    const float* Wo2  = (const float*)d_in[15];
    const float* bo2  = (const float*)d_in[16];
    const float* Wout = (const float*)d_in[17];
    const float* bout = (const float*)d_in[18];

    fused_kernel<<<dim3(BN), dim3(256), 0, stream>>>(
        x, Ws1, bs1, Ws2, bs2, Wa1, ba1, Wa2,
        Wih, bih, bhh, Wo1, bo1, Wo2, bo2, Wout, bout,
        (float*)d_out);
}

// Round 5
// 167.042 us; speedup vs baseline: 1.1970x; 1.0141x over previous
//
#include <hip/hip_runtime.h>

// Problem: B=32, N=128, T=96, H=64, TF=24. All I/O float32.
// A_norm = ones(N,N)/N => every GCN output is the node-mean (node-uniform);
// the model collapses to per-batch H-vectors. Node dim appears only in the
// initial mean over nodes and the final broadcast.
//
// R4 post-mortem: VGPR=80 => ODE weight arrays (128 floats) were NOT register
// resident; compiler's pressure heuristic targets multi-wave occupancy.
// Fix: amdgpu_waves_per_eu(1,1) (4-wave block = exactly 1 wave/SIMD; blocks
// never co-reside at 32 blocks / 256 CUs) => ~512-VGPR budget, weights hoist.
// Phase-1 weight arrays are brace-scoped so their liveness ends before the
// ODE weights load.

#define BN 32
#define NN 128
#define TT 96
#define HH 64
#define TFC 24

__device__ __forceinline__ float rdl(float v, int l) {
    return __int_as_float(__builtin_amdgcn_readlane(__float_as_int(v), l));
}
__device__ __forceinline__ float fast_tanh(float x) {
    x = fminf(fmaxf(x, -15.f), 15.f);
    float e = __expf(2.f * x);
    return (e - 1.f) / (e + 1.f);
}
__device__ __forceinline__ float fast_sigmoid(float x) {
    return 1.f / (1.f + __expf(-x));
}
__device__ __forceinline__ float wave_sum(float v) {
#pragma unroll
    for (int off = 32; off > 0; off >>= 1) v += __shfl_xor(v, off, 64);
    return v;
}
__device__ __forceinline__ float wave_max(float v) {
#pragma unroll
    for (int off = 32; off > 0; off >>= 1) v = fmaxf(v, __shfl_xor(v, off, 64));
    return v;
}

__global__ __launch_bounds__(256)
__attribute__((amdgpu_waves_per_eu(1, 1)))
void fused_kernel(
    const float* __restrict__ x,    const float* __restrict__ Ws1,
    const float* __restrict__ bs1,  const float* __restrict__ Ws2,
    const float* __restrict__ bs2,  const float* __restrict__ Wa1,
    const float* __restrict__ ba1,  const float* __restrict__ Wa2,
    const float* __restrict__ Wih,  const float* __restrict__ bih,
    const float* __restrict__ bhh,  const float* __restrict__ Wo1,
    const float* __restrict__ bo1p, const float* __restrict__ Wo2,
    const float* __restrict__ bo2p, const float* __restrict__ Wout,
    const float* __restrict__ boutp, float* __restrict__ out)
{
    const int tid  = threadIdx.x;
    const int lane = tid & 63;
    const int w    = tid >> 6;
    const int b    = blockIdx.x;

    __shared__ float xbar[TT];
    __shared__ float h2s[TT][HH];
    __shared__ float atts[TT];

    // ---- phase 0: xbar[t] = mean_n x[b,n,t] (coalesced across threads) ----
    if (tid < TT) {
        const float* xb = x + (size_t)b * NN * TT + tid;
        float s = 0.f;
#pragma unroll
        for (int n = 0; n < NN; ++n) s += xb[n * TT];
        xbar[tid] = s * (1.f / 128.f);
    }

    {   // ======== phase 1 scope: its 128-float weight arrays die here ========
        const float ws1l = Ws1[lane];
        const float bs1l = bs1[lane];
        const float bs2l = bs2[lane];
        const float ba1l = ba1[lane];
        const float wa2l = Wa2[lane];
        float ws2c[HH], wa1c[HH];
#pragma unroll
        for (int h = 0; h < HH; ++h) {
            ws2c[h] = Ws2[h * HH + lane];
            wa1c[h] = Wa1[h * HH + lane];
        }
        __syncthreads();   // barrier 1: xbar ready

        // spatial GCN + attention logits, 24 t per wave, readlane broadcasts
#pragma unroll 1
        for (int i = 0; i < TT / 4; ++i) {
            const int t = w * (TT / 4) + i;
            const float s = xbar[t];
            const float h1 = fmaxf(fmaf(s, ws1l, bs1l), 0.f);  // lane = h
            float a0 = bs2l, a1 = 0.f, a2 = 0.f, a3 = 0.f;
#pragma unroll
            for (int h = 0; h < HH; h += 4) {
                a0 = fmaf(rdl(h1, h),     ws2c[h],     a0);
                a1 = fmaf(rdl(h1, h + 1), ws2c[h + 1], a1);
                a2 = fmaf(rdl(h1, h + 2), ws2c[h + 2], a2);
                a3 = fmaf(rdl(h1, h + 3), ws2c[h + 3], a3);
            }
            const float h2v = fmaxf((a0 + a1) + (a2 + a3), 0.f);
            h2s[t][lane] = h2v;

            a0 = ba1l; a1 = 0.f; a2 = 0.f; a3 = 0.f;
#pragma unroll
            for (int h = 0; h < HH; h += 4) {
                a0 = fmaf(rdl(h2v, h),     wa1c[h],     a0);
                a1 = fmaf(rdl(h2v, h + 1), wa1c[h + 1], a1);
                a2 = fmaf(rdl(h2v, h + 2), wa1c[h + 2], a2);
                a3 = fmaf(rdl(h2v, h + 3), wa1c[h + 3], a3);
            }
            const float g = fast_tanh((a0 + a1) + (a2 + a3));
            const float att = wave_sum(g * wa2l);      // ba2: shift-invariant
            if (lane == 0) atts[t] = att;
        }
    }   // ======== end phase 1 scope ========
    __syncthreads();   // barrier 2: h2s, atts ready

    if (w != 0) return;   // waves 1-3 done; no barriers below

    // ================= wave 0 only: softmax + nf + GRU + ODE =================
    const float a0s = atts[lane];
    const float a1s = (lane < TT - 64) ? atts[64 + lane] : -1e30f;
    const float m = wave_max(fmaxf(a0s, a1s));
    const float e0 = __expf(a0s - m);
    const float e1 = (lane < TT - 64) ? __expf(a1s - m) : 0.f;
    const float inv = 1.f / wave_sum(e0 + e1);
    const float q0 = e0 * inv;
    const float q1 = e1 * inv;

    // nf[lane] = sum_t w[t] * h2[t][lane]
    float nf = 0.f;
#pragma unroll
    for (int t = 0; t < 64; ++t) nf = fmaf(rdl(q0, t), h2s[t][lane], nf);
#pragma unroll
    for (int t = 0; t < 32; ++t) nf = fmaf(rdl(q1, t), h2s[64 + t][lane], nf);

    // one-step GRU, h0=0 (W_hh matmul vanishes; b_hh biases remain)
    float gr = bih[lane];
    float gz = bih[64 + lane];
    float gn = bih[128 + lane];
#pragma unroll
    for (int j = 0; j < HH; j += 4) {
        const float4 wr = *(const float4*)&Wih[(size_t)lane * HH + j];
        const float4 wz = *(const float4*)&Wih[(size_t)(64 + lane) * HH + j];
        const float4 wn = *(const float4*)&Wih[(size_t)(128 + lane) * HH + j];
        const float n0 = rdl(nf, j), n1 = rdl(nf, j + 1);
        const float n2 = rdl(nf, j + 2), n3 = rdl(nf, j + 3);
        gr += n0 * wr.x + n1 * wr.y + n2 * wr.z + n3 * wr.w;
        gz += n0 * wz.x + n1 * wz.y + n2 * wz.z + n3 * wz.w;
        gn += n0 * wn.x + n1 * wn.y + n2 * wn.z + n3 * wn.w;
    }
    const float r = fast_sigmoid(gr + bhh[lane]);
    const float z = fast_sigmoid(gz + bhh[64 + lane]);
    const float n = fast_tanh(gn + r * bhh[128 + lane]);
    float y = (1.f - z) * n;

    // ODE weights: loaded after phase-1 arrays are dead (disjoint liveness)
    float w1c[HH], w2c[HH];
#pragma unroll
    for (int h = 0; h < HH; ++h) {
        w1c[h] = Wo1[h * HH + lane];
        w2c[h] = Wo2[h * HH + lane];
    }
    const float bo1 = bo1p[lane];
    const float bo2 = bo2p[lane];
    const float wo  = Wout[lane];
    const float bo  = boutp[0];

    // f(u) = tanh( tanh(u@W1+b1) @ W2 + b2 ) — registers + readlane only
    auto f_eval = [&](float u) -> float {
        float c0 = bo1, c1 = 0.f, c2 = 0.f, c3 = 0.f;
#pragma unroll
        for (int h = 0; h < HH; h += 4) {
            c0 = fmaf(rdl(u, h),     w1c[h],     c0);
            c1 = fmaf(rdl(u, h + 1), w1c[h + 1], c1);
            c2 = fmaf(rdl(u, h + 2), w1c[h + 2], c2);
            c3 = fmaf(rdl(u, h + 3), w1c[h + 3], c3);
        }
        const float v = fast_tanh((c0 + c1) + (c2 + c3));
        c0 = bo2; c1 = 0.f; c2 = 0.f; c3 = 0.f;
#pragma unroll
        for (int h = 0; h < HH; h += 4) {
            c0 = fmaf(rdl(v, h),     w2c[h],     c0);
            c1 = fmaf(rdl(v, h + 1), w2c[h + 1], c1);
            c2 = fmaf(rdl(v, h + 2), w2c[h + 2], c2);
            c3 = fmaf(rdl(v, h + 3), w2c[h + 3], c3);
        }
        return fast_tanh((c0 + c1) + (c2 + c3));
    };

    // output head: p is uniform across lanes after wave_sum; store directly.
    float* ob = out + (size_t)b * NN * TFC;
    {
        const float p = wave_sum(y * wo) + bo;         // traj[0] = hidden
        ob[lane * TFC]        = p;                     // n = lane
        ob[(64 + lane) * TFC] = p;                     // n = lane+64
    }

    const float dt = (float)(24.0 / 23.0);
    const float third = 1.f / 3.f;

#pragma unroll 1
    for (int st = 0; st < TFC - 1; ++st) {
        const float k1 = f_eval(y);
        const float k2 = f_eval(y + dt * k1 * third);
        const float k3 = f_eval(y + dt * (k2 - k1 * third));
        const float k4 = f_eval(y + dt * (k1 - k2 + k3));
        y = y + dt * (k1 + 3.f * (k2 + k3) + k4) * 0.125f;
        const float p = wave_sum(y * wo) + bo;
        ob[lane * TFC + st + 1]        = p;
        ob[(64 + lane) * TFC + st + 1] = p;
    }
}

extern "C" void kernel_launch(void* const* d_in, const int* in_sizes, int n_in,
                              void* d_out, int out_size, void* d_ws, size_t ws_size,
                              hipStream_t stream) {
    (void)in_sizes; (void)n_in; (void)d_ws; (void)ws_size; (void)out_size;
    const float* x    = (const float*)d_in[0];
    const float* Ws1  = (const float*)d_in[1];
    const float* bs1  = (const float*)d_in[2];
    const float* Ws2  = (const float*)d_in[3];
    const float* bs2  = (const float*)d_in[4];
    const float* Wa1  = (const float*)d_in[5];
    const float* ba1  = (const float*)d_in[6];
    const float* Wa2  = (const float*)d_in[7];
    // d_in[8]  = ba2  : unused (softmax shift-invariant)
    const float* Wih  = (const float*)d_in[9];
    // d_in[10] = W_hh : unused (h0 = 0)
    const float* bih  = (const float*)d_in[11];
    const float* bhh  = (const float*)d_in[12];
    const float* Wo1  = (const float*)d_in[13];
    const float* bo1  = (const float*)d_in[14];
    const float* Wo2  = (const float*)d_in[15];
    const float* bo2  = (const float*)d_in[16];
    const float* Wout = (const float*)d_in[17];
    const float* bout = (const float*)d_in[18];

    fused_kernel<<<dim3(BN), dim3(256), 0, stream>>>(
        x, Ws1, bs1, Ws2, bs2, Wa1, ba1, Wa2,
        Wih, bih, bhh, Wo1, bo1, Wo2, bo2, Wout, bout,
        (float*)d_out);
}

// Round 6
// 166.746 us; speedup vs baseline: 1.1991x; 1.0018x over previous
//
#include <hip/hip_runtime.h>

// Problem: B=32, N=128, T=96, H=64, TF=24. All I/O float32.
// A_norm = ones(N,N)/N => every GCN output is the node-mean (node-uniform);
// model collapses to per-batch H-vectors. Node dim appears only in the
// initial mean and the final broadcast.
//
// R5 post-mortem: VGPR=132, dur unchanged => pre-RA scheduler keeps sinking
// the (rematerializable) weight loads back into the 92-f_eval loop.
// Fix: pin every weight element in a VGPR with an empty asm "+v" constraint
// right after its load — non-rematerializable => must stay live => true
// register residency across the sequential ODE chain.

#define BN 32
#define NN 128
#define TT 96
#define HH 64
#define TFC 24

__device__ __forceinline__ float rdl(float v, int l) {
    return __int_as_float(__builtin_amdgcn_readlane(__float_as_int(v), l));
}
__device__ __forceinline__ float fast_tanh(float x) {
    x = fminf(fmaxf(x, -15.f), 15.f);
    float e = __expf(2.f * x);
    return (e - 1.f) / (e + 1.f);
}
__device__ __forceinline__ float fast_sigmoid(float x) {
    return 1.f / (1.f + __expf(-x));
}
__device__ __forceinline__ float wave_sum(float v) {
#pragma unroll
    for (int off = 32; off > 0; off >>= 1) v += __shfl_xor(v, off, 64);
    return v;
}
__device__ __forceinline__ float wave_max(float v) {
#pragma unroll
    for (int off = 32; off > 0; off >>= 1) v = fmaxf(v, __shfl_xor(v, off, 64));
    return v;
}

__global__ __launch_bounds__(256)
__attribute__((amdgpu_waves_per_eu(1, 1)))
void fused_kernel(
    const float* __restrict__ x,    const float* __restrict__ Ws1,
    const float* __restrict__ bs1,  const float* __restrict__ Ws2,
    const float* __restrict__ bs2,  const float* __restrict__ Wa1,
    const float* __restrict__ ba1,  const float* __restrict__ Wa2,
    const float* __restrict__ Wih,  const float* __restrict__ bih,
    const float* __restrict__ bhh,  const float* __restrict__ Wo1,
    const float* __restrict__ bo1p, const float* __restrict__ Wo2,
    const float* __restrict__ bo2p, const float* __restrict__ Wout,
    const float* __restrict__ boutp, float* __restrict__ out)
{
    const int tid  = threadIdx.x;
    const int lane = tid & 63;
    const int w    = tid >> 6;
    const int b    = blockIdx.x;

    __shared__ float xbar[TT];
    __shared__ float h2s[TT][HH];
    __shared__ float atts[TT];

    // ---- phase 0: xbar[t] = mean_n x[b,n,t] (t-contiguous => coalesced) ----
    if (tid < TT) {
        const float* xb = x + (size_t)b * NN * TT + tid;
        float s = 0.f;
#pragma unroll
        for (int n = 0; n < NN; ++n) s += xb[n * TT];
        xbar[tid] = s * (1.f / 128.f);
    }

    {   // ======== phase 1 scope: weight arrays die at the closing brace ======
        const float ws1l = Ws1[lane];
        const float bs1l = bs1[lane];
        const float bs2l = bs2[lane];
        const float ba1l = ba1[lane];
        const float wa2l = Wa2[lane];
        float ws2c[HH], wa1c[HH];
#pragma unroll
        for (int h = 0; h < HH; ++h) {
            ws2c[h] = Ws2[h * HH + lane];
            wa1c[h] = Wa1[h * HH + lane];
        }
        // pin: non-rematerializable => stays in VGPRs through the loop below
#pragma unroll
        for (int h = 0; h < HH; ++h) {
            asm volatile("" : "+v"(ws2c[h]), "+v"(wa1c[h]));
        }
        __syncthreads();   // barrier 1: xbar ready

        // spatial GCN + attention logits, 24 t per wave, readlane broadcasts
#pragma unroll 1
        for (int i = 0; i < TT / 4; ++i) {
            const int t = w * (TT / 4) + i;
            const float s = xbar[t];
            const float h1 = fmaxf(fmaf(s, ws1l, bs1l), 0.f);  // lane = h
            float a0 = bs2l, a1 = 0.f, a2 = 0.f, a3 = 0.f;
#pragma unroll
            for (int h = 0; h < HH; h += 4) {
                a0 = fmaf(rdl(h1, h),     ws2c[h],     a0);
                a1 = fmaf(rdl(h1, h + 1), ws2c[h + 1], a1);
                a2 = fmaf(rdl(h1, h + 2), ws2c[h + 2], a2);
                a3 = fmaf(rdl(h1, h + 3), ws2c[h + 3], a3);
            }
            const float h2v = fmaxf((a0 + a1) + (a2 + a3), 0.f);
            h2s[t][lane] = h2v;

            a0 = ba1l; a1 = 0.f; a2 = 0.f; a3 = 0.f;
#pragma unroll
            for (int h = 0; h < HH; h += 4) {
                a0 = fmaf(rdl(h2v, h),     wa1c[h],     a0);
                a1 = fmaf(rdl(h2v, h + 1), wa1c[h + 1], a1);
                a2 = fmaf(rdl(h2v, h + 2), wa1c[h + 2], a2);
                a3 = fmaf(rdl(h2v, h + 3), wa1c[h + 3], a3);
            }
            const float g = fast_tanh((a0 + a1) + (a2 + a3));
            const float att = wave_sum(g * wa2l);      // ba2: shift-invariant
            if (lane == 0) atts[t] = att;
        }
    }   // ======== end phase 1 scope ========
    __syncthreads();   // barrier 2: h2s, atts ready

    if (w != 0) return;   // waves 1-3 done; no barriers below

    // ================= wave 0 only: softmax + nf + GRU + ODE =================
    const float a0s = atts[lane];
    const float a1s = (lane < TT - 64) ? atts[64 + lane] : -1e30f;
    const float m = wave_max(fmaxf(a0s, a1s));
    const float e0 = __expf(a0s - m);
    const float e1 = (lane < TT - 64) ? __expf(a1s - m) : 0.f;
    const float inv = 1.f / wave_sum(e0 + e1);
    const float q0 = e0 * inv;
    const float q1 = e1 * inv;

    // nf[lane] = sum_t w[t] * h2[t][lane]
    float nf = 0.f;
#pragma unroll
    for (int t = 0; t < 64; ++t) nf = fmaf(rdl(q0, t), h2s[t][lane], nf);
#pragma unroll
    for (int t = 0; t < 32; ++t) nf = fmaf(rdl(q1, t), h2s[64 + t][lane], nf);

    // one-step GRU, h0=0 (W_hh matmul vanishes; b_hh biases remain)
    float gr = bih[lane];
    float gz = bih[64 + lane];
    float gn = bih[128 + lane];
#pragma unroll
    for (int j = 0; j < HH; j += 4) {
        const float4 wr = *(const float4*)&Wih[(size_t)lane * HH + j];
        const float4 wz = *(const float4*)&Wih[(size_t)(64 + lane) * HH + j];
        const float4 wn = *(const float4*)&Wih[(size_t)(128 + lane) * HH + j];
        const float n0 = rdl(nf, j), n1 = rdl(nf, j + 1);
        const float n2 = rdl(nf, j + 2), n3 = rdl(nf, j + 3);
        gr += n0 * wr.x + n1 * wr.y + n2 * wr.z + n3 * wr.w;
        gz += n0 * wz.x + n1 * wz.y + n2 * wz.z + n3 * wz.w;
        gn += n0 * wn.x + n1 * wn.y + n2 * wn.z + n3 * wn.w;
    }
    const float r = fast_sigmoid(gr + bhh[lane]);
    const float z = fast_sigmoid(gz + bhh[64 + lane]);
    const float n = fast_tanh(gn + r * bhh[128 + lane]);
    float y = (1.f - z) * n;

    // ODE weights: load then PIN in VGPRs (disjoint from phase-1 arrays)
    float w1c[HH], w2c[HH];
#pragma unroll
    for (int h = 0; h < HH; ++h) {
        w1c[h] = Wo1[h * HH + lane];
        w2c[h] = Wo2[h * HH + lane];
    }
#pragma unroll
    for (int h = 0; h < HH; ++h) {
        asm volatile("" : "+v"(w1c[h]), "+v"(w2c[h]));
    }
    const float bo1 = bo1p[lane];
    const float bo2 = bo2p[lane];
    const float wo  = Wout[lane];
    const float bo  = boutp[0];

    // f(u) = tanh( tanh(u@W1+b1) @ W2 + b2 ) — registers + readlane only
    auto f_eval = [&](float u) -> float {
        float c0 = bo1, c1 = 0.f, c2 = 0.f, c3 = 0.f;
#pragma unroll
        for (int h = 0; h < HH; h += 4) {
            c0 = fmaf(rdl(u, h),     w1c[h],     c0);
            c1 = fmaf(rdl(u, h + 1), w1c[h + 1], c1);
            c2 = fmaf(rdl(u, h + 2), w1c[h + 2], c2);
            c3 = fmaf(rdl(u, h + 3), w1c[h + 3], c3);
        }
        const float v = fast_tanh((c0 + c1) + (c2 + c3));
        c0 = bo2; c1 = 0.f; c2 = 0.f; c3 = 0.f;
#pragma unroll
        for (int h = 0; h < HH; h += 4) {
            c0 = fmaf(rdl(v, h),     w2c[h],     c0);
            c1 = fmaf(rdl(v, h + 1), w2c[h + 1], c1);
            c2 = fmaf(rdl(v, h + 2), w2c[h + 2], c2);
            c3 = fmaf(rdl(v, h + 3), w2c[h + 3], c3);
        }
        return fast_tanh((c0 + c1) + (c2 + c3));
    };

    // output head: p is uniform across lanes after wave_sum; store directly.
    float* ob = out + (size_t)b * NN * TFC;
    {
        const float p = wave_sum(y * wo) + bo;         // traj[0] = hidden
        ob[lane * TFC]        = p;                     // n = lane
        ob[(64 + lane) * TFC] = p;                     // n = lane+64
    }

    const float dt = (float)(24.0 / 23.0);
    const float third = 1.f / 3.f;

#pragma unroll 1
    for (int st = 0; st < TFC - 1; ++st) {
        const float k1 = f_eval(y);
        const float k2 = f_eval(y + dt * k1 * third);
        const float k3 = f_eval(y + dt * (k2 - k1 * third));
        const float k4 = f_eval(y + dt * (k1 - k2 + k3));
        y = y + dt * (k1 + 3.f * (k2 + k3) + k4) * 0.125f;
        const float p = wave_sum(y * wo) + bo;
        ob[lane * TFC + st + 1]        = p;
        ob[(64 + lane) * TFC + st + 1] = p;
    }
}

extern "C" void kernel_launch(void* const* d_in, const int* in_sizes, int n_in,
                              void* d_out, int out_size, void* d_ws, size_t ws_size,
                              hipStream_t stream) {
    (void)in_sizes; (void)n_in; (void)d_ws; (void)ws_size; (void)out_size;
    const float* x    = (const float*)d_in[0];
    const float* Ws1  = (const float*)d_in[1];
    const float* bs1  = (const float*)d_in[2];
    const float* Ws2  = (const float*)d_in[3];
    const float* bs2  = (const float*)d_in[4];
    const float* Wa1  = (const float*)d_in[5];
    const float* ba1  = (const float*)d_in[6];
    const float* Wa2  = (const float*)d_in[7];
    // d_in[8]  = ba2  : unused (softmax shift-invariant)
    const float* Wih  = (const float*)d_in[9];
    // d_in[10] = W_hh : unused (h0 = 0)
    const float* bih  = (const float*)d_in[11];
    const float* bhh  = (const float*)d_in[12];
    const float* Wo1  = (const float*)d_in[13];
    const float* bo1  = (const float*)d_in[14];
    const float* Wo2  = (const float*)d_in[15];
    const float* bo2  = (const float*)d_in[16];
    const float* Wout = (const float*)d_in[17];
    const float* bout = (const float*)d_in[18];

    fused_kernel<<<dim3(BN), dim3(256), 0, stream>>>(
        x, Ws1, bs1, Ws2, bs2, Wa1, ba1, Wa2,
        Wih, bih, bhh, Wo1, bo1, Wo2, bo2, Wout, bout,
        (float*)d_out);
}